// Round 2
// baseline (104.188 us; speedup 1.0000x reference)
//
#include <hip/hip_runtime.h>

#define NB 64        // bins
#define HW 65536     // pixels per channel (256*256)
#define NCH 24       // B*C = 8*3
#define SPLIT 16     // segments per channel-image

// Kernel A: soft histogram. grid = (SPLIT, 2*NCH), block = 256.
// Each block accumulates a 64-bin partial histogram for a 4096-pixel segment
// of one channel of pred (ct < NCH) or target (ct >= NCH) and writes it to
// part[ct][seg][bin]. No atomics, no pre-zeroed memory required.
__global__ __launch_bounds__(256) void chml_hist(const float* __restrict__ pred,
                                                 const float* __restrict__ targ,
                                                 float* __restrict__ part) {
  const int seg = blockIdx.x;   // 0..SPLIT-1
  const int ct  = blockIdx.y;   // 0..2*NCH-1
  const float* src = (ct < NCH) ? (pred + (size_t)ct * HW)
                                : (targ + (size_t)(ct - NCH) * HW);
  const int tid  = threadIdx.x;
  const int lane = tid & 63;
  const int wave = tid >> 6;

  float acc[NB];
#pragma unroll
  for (int j = 0; j < NB; ++j) acc[j] = 0.0f;

  // segment = 4096 elems = 1024 float4; 256 threads x 4 iterations, coalesced
  const float4* s4 = (const float4*)(src + (size_t)seg * (HW / SPLIT));
  for (int k = 0; k < 4; ++k) {
    float4 p = s4[k * 256 + tid];
#pragma unroll
    for (int j = 0; j < NB; ++j) {
      const float c = (float)j * (1.0f / 63.0f);   // bin center j/63
      float t0 = p.x - c;
      float t1 = p.y - c;
      float t2 = p.z - c;
      float t3 = p.w - c;
      // exp(-(x-c)^2 / (2*(1/64)^2)) = exp(-2048*(x-c)^2)
      acc[j] += __expf(t0 * t0 * -2048.0f) + __expf(t1 * t1 * -2048.0f) +
                __expf(t2 * t2 * -2048.0f) + __expf(t3 * t3 * -2048.0f);
    }
  }

  // per-bin wave butterfly reduction (all 64 lanes end with the wave total)
#pragma unroll
  for (int j = 0; j < NB; ++j) {
    float v = acc[j];
    v += __shfl_xor(v, 32, 64);
    v += __shfl_xor(v, 16, 64);
    v += __shfl_xor(v, 8, 64);
    v += __shfl_xor(v, 4, 64);
    v += __shfl_xor(v, 2, 64);
    v += __shfl_xor(v, 1, 64);
    acc[j] = v;
  }

  __shared__ float lds[4][NB];
  if (lane == 0) {
#pragma unroll
    for (int j = 0; j < NB; ++j) lds[wave][j] = acc[j];
  }
  __syncthreads();
  if (tid < NB) {
    float v = lds[0][tid] + lds[1][tid] + lds[2][tid] + lds[3][tid];
    part[((size_t)ct * SPLIT + seg) * NB + tid] = v;
  }
}

// Kernel B: sum segment partials, normalize, cumsum, mean |diff|.
// 1 block, 8 waves; lane = bin.
__global__ __launch_bounds__(512) void chml_finish(const float* __restrict__ part,
                                                   float* __restrict__ out) {
  const int tid  = threadIdx.x;
  const int lane = tid & 63;
  const int wave = tid >> 6;  // 0..7
  float lsum = 0.0f;
  for (int c = wave; c < NCH; c += 8) {
    float vp = 0.0f, vt = 0.0f;
#pragma unroll
    for (int s = 0; s < SPLIT; ++s) {
      vp += part[((size_t)c * SPLIT + s) * NB + lane];
      vt += part[((size_t)(c + NCH) * SPLIT + s) * NB + lane];
    }
    // inclusive prefix scan across 64 lanes (Hillis-Steele)
#pragma unroll
    for (int off = 1; off < 64; off <<= 1) {
      float up = __shfl_up(vp, off, 64);
      float ut = __shfl_up(vt, off, 64);
      if (lane >= off) { vp += up; vt += ut; }
    }
    float totp = __shfl(vp, 63, 64);
    float tott = __shfl(vt, 63, 64);
    lsum += fabsf(vp / (totp + 1e-7f) - vt / (tott + 1e-7f));
  }
  // reduce loss over lanes
#pragma unroll
  for (int off = 32; off >= 1; off >>= 1) lsum += __shfl_xor(lsum, off, 64);
  __shared__ float red[8];
  if (lane == 0) red[wave] = lsum;
  __syncthreads();
  if (tid == 0) {
    float t = red[0] + red[1] + red[2] + red[3] +
              red[4] + red[5] + red[6] + red[7];
    out[0] = t * (1.0f / (float)(NCH * NB));
  }
}

extern "C" void kernel_launch(void* const* d_in, const int* in_sizes, int n_in,
                              void* d_out, int out_size, void* d_ws, size_t ws_size,
                              hipStream_t stream) {
  const float* pred = (const float*)d_in[0];
  const float* targ = (const float*)d_in[1];
  float* part = (float*)d_ws;  // 2*NCH*SPLIT*NB floats = 196 KB

  dim3 grid(SPLIT, 2 * NCH);
  chml_hist<<<grid, 256, 0, stream>>>(pred, targ, part);
  chml_finish<<<1, 512, 0, stream>>>(part, (float*)d_out);
}

// Round 3
// 100.467 us; speedup vs baseline: 1.0370x; 1.0370x over previous
//
#include <hip/hip_runtime.h>

#define NB 64        // bins
#define HW 65536     // pixels per channel (256*256)
#define NCH 24       // B*C = 8*3
#define SPLIT 32     // segments per channel-image

// Soft-histogram weight: w_j(x) = exp(-2048*(x - j/63)^2), j = 0..63.
// With f = 63x, K = 2048/3969:  w_j = exp(-K*(f-j)^2).
// Adjacent-bin ratio: w_{j+1}/w_j = exp(K*(2f-2j-1)) =: M_j,  M_{j+1} = M_j * R,
// R = exp(-2K). Recurrence restarted with a direct exp every 8 bins so that
// underflow (w -> 0 at |f-j| > ~13) can never wipe out a significant group:
// if a group's start underflows, every member is < exp(-K*36) ~ 4e-10.
__global__ __launch_bounds__(256) void chml_hist(const float* __restrict__ pred,
                                                 const float* __restrict__ targ,
                                                 float* __restrict__ part) {
  const int seg = blockIdx.x;   // 0..SPLIT-1
  const int ct  = blockIdx.y;   // 0..2*NCH-1
  const float* src = (ct < NCH) ? (pred + (size_t)ct * HW)
                                : (targ + (size_t)(ct - NCH) * HW);
  const int tid  = threadIdx.x;
  const int lane = tid & 63;
  const int wave = tid >> 6;

  const float K  = 0.51599899f;       // 2048/3969
  const float R  = __expf(-2.0f * K); // per-bin decay of the multiplier

  float acc[NB];
#pragma unroll
  for (int j = 0; j < NB; ++j) acc[j] = 0.0f;

  // segment = 2048 elems = 512 float4; 256 threads x 2 iterations, coalesced
  const float4* s4 = (const float4*)(src + (size_t)seg * (HW / SPLIT));
#pragma unroll
  for (int k = 0; k < (HW / SPLIT) / (4 * 256); ++k) {
    float4 p = s4[k * 256 + tid];
    float f0 = p.x * 63.0f, f1 = p.y * 63.0f, f2 = p.z * 63.0f, f3 = p.w * 63.0f;
    // M = exp(K*(2f-1)) — multiplier for step j=0
    float M0 = __expf(fmaf(f0, 2.0f * K, -K));
    float M1 = __expf(fmaf(f1, 2.0f * K, -K));
    float M2 = __expf(fmaf(f2, 2.0f * K, -K));
    float M3 = __expf(fmaf(f3, 2.0f * K, -K));
#pragma unroll
    for (int m = 0; m < 8; ++m) {
      const float c = (float)(8 * m);
      float u0 = f0 - c, u1 = f1 - c, u2 = f2 - c, u3 = f3 - c;
      float w0 = __expf(u0 * u0 * -K);
      float w1 = __expf(u1 * u1 * -K);
      float w2 = __expf(u2 * u2 * -K);
      float w3 = __expf(u3 * u3 * -K);
      acc[8 * m] += (w0 + w1) + (w2 + w3);
#pragma unroll
      for (int r = 1; r < 8; ++r) {
        w0 *= M0; w1 *= M1; w2 *= M2; w3 *= M3;
        M0 *= R;  M1 *= R;  M2 *= R;  M3 *= R;
        acc[8 * m + r] += (w0 + w1) + (w2 + w3);
      }
      M0 *= R; M1 *= R; M2 *= R; M3 *= R;  // account for the skipped step
    }
  }

  // Staged-halving cross-lane reduction: 63 shuffles total.
  // Invariant: after stage k, acc[t] (t < 64>>(k+1)) holds the partial sum of
  // bin (t<<(k+1) | (lane & (2^(k+1)-1))) over lanes differing in bits 0..k.
  // After 6 stages, acc[0] = total for bin `lane`.
#pragma unroll
  for (int k = 0; k < 6; ++k) {
    const int msk = 1 << k;
    const bool hi = (lane & msk) != 0;
#pragma unroll
    for (int t = 0; t < (32 >> k); ++t) {
      float a = acc[2 * t], b = acc[2 * t + 1];
      float mine  = hi ? b : a;
      float other = hi ? a : b;
      acc[t] = mine + __shfl_xor(other, msk, 64);
    }
  }

  __shared__ float lds[4][NB];
  lds[wave][lane] = acc[0];
  __syncthreads();
  if (tid < NB) {
    part[((size_t)ct * SPLIT + seg) * NB + tid] =
        (lds[0][tid] + lds[1][tid]) + (lds[2][tid] + lds[3][tid]);
  }
}

// Kernel B: sum segment partials, normalize, cumsum, mean |diff|.
// 1 block, 8 waves; lane = bin.
__global__ __launch_bounds__(512) void chml_finish(const float* __restrict__ part,
                                                   float* __restrict__ out) {
  const int tid  = threadIdx.x;
  const int lane = tid & 63;
  const int wave = tid >> 6;  // 0..7
  float lsum = 0.0f;
  for (int c = wave; c < NCH; c += 8) {
    float vp = 0.0f, vt = 0.0f;
#pragma unroll
    for (int s = 0; s < SPLIT; ++s) {
      vp += part[((size_t)c * SPLIT + s) * NB + lane];
      vt += part[((size_t)(c + NCH) * SPLIT + s) * NB + lane];
    }
    // inclusive prefix scan across 64 lanes (Hillis-Steele)
#pragma unroll
    for (int off = 1; off < 64; off <<= 1) {
      float up = __shfl_up(vp, off, 64);
      float ut = __shfl_up(vt, off, 64);
      if (lane >= off) { vp += up; vt += ut; }
    }
    float totp = __shfl(vp, 63, 64);
    float tott = __shfl(vt, 63, 64);
    lsum += fabsf(vp / (totp + 1e-7f) - vt / (tott + 1e-7f));
  }
  // reduce loss over lanes
#pragma unroll
  for (int off = 32; off >= 1; off >>= 1) lsum += __shfl_xor(lsum, off, 64);
  __shared__ float red[8];
  if (lane == 0) red[wave] = lsum;
  __syncthreads();
  if (tid == 0) {
    float t = (red[0] + red[1]) + (red[2] + red[3]) +
              (red[4] + red[5]) + (red[6] + red[7]);
    out[0] = t * (1.0f / (float)(NCH * NB));
  }
}

extern "C" void kernel_launch(void* const* d_in, const int* in_sizes, int n_in,
                              void* d_out, int out_size, void* d_ws, size_t ws_size,
                              hipStream_t stream) {
  const float* pred = (const float*)d_in[0];
  const float* targ = (const float*)d_in[1];
  float* part = (float*)d_ws;  // 2*NCH*SPLIT*NB floats = 384 KB

  dim3 grid(SPLIT, 2 * NCH);
  chml_hist<<<grid, 256, 0, stream>>>(pred, targ, part);
  chml_finish<<<1, 512, 0, stream>>>(part, (float*)d_out);
}